// Round 1
// baseline (497.488 us; speedup 1.0000x reference)
//
#include <hip/hip_runtime.h>
#include <math.h>

// Problem constants (from reference)
#define BATCH   8192
#define NBULK   62
#define DD      64
#define DP      68          // padded LDS row stride (floats)
#define SPB     32          // samples per psi block
#define TPB     512

// ws float-offsets (ws must be >= 40 KB; only first 64 B needs zeroing)
#define WS_PSISUM 0
#define WS_LSF    1
#define WS_LSB    2
#define WS_E      1024
#define WS_B      6144

#define FMA4(acc, s, v)                                   \
    do {                                                  \
        acc.x = fmaf((s), (v).x, acc.x);                  \
        acc.y = fmaf((s), (v).y, acc.y);                  \
        acc.z = fmaf((s), (v).z, acc.z);                  \
        acc.w = fmaf((s), (v).w, acc.w);                  \
    } while (0)

extern "C" __global__ __launch_bounds__(TPB)
void mps_main(const int* __restrict__ cfgG, const float* __restrict__ leftG,
              const float* __restrict__ bulkG, const float* __restrict__ rightG,
              float* __restrict__ wsF)
{
    extern __shared__ char smem[];
    const int tid = threadIdx.x;
    const int bid = blockIdx.x;

    if (bid >= 2) {
        // ---------------- psi role: 32 samples per block ----------------
        float* Ml  = (float*)smem;                    // 8192 floats (site, both branches, raw layout)
        float* env = Ml + 8192;                       // 32 x DP
        int*   cfg = (int*)(env + SPB * DP);          // 32 x 64
        float* red = (float*)(cfg + SPB * 64);        // 32 x 16

        const int s  = tid >> 4;                      // 0..31 sample-in-block
        const int c  = tid & 15;                      // 0..15 col group (4 cols)
        const int c4 = c * 4;
        const int s0 = (bid - 2) * SPB;

        for (int idx = tid; idx < SPB * 64; idx += TPB)
            cfg[idx] = cfgG[s0 * 64 + idx];
        __syncthreads();

        {   // env0 = left[cfg[:,0]]
            const int sel0 = cfg[s * 64 + 0];
            float4 v = *(const float4*)&leftG[sel0 * 64 + c4];
            *(float4*)&env[s * DP + c4] = v;
        }

        for (int site = 0; site < NBULK; ++site) {
            const float4* Mg4 = (const float4*)(bulkG + (size_t)site * 8192);
            for (int idx = tid; idx < 2048; idx += TPB)
                ((float4*)Ml)[idx] = Mg4[idx];
            __syncthreads();  // Ml ready; env writes from prev site visible

            const int sel = cfg[s * 64 + site + 1];
            float4 acc = make_float4(0.f, 0.f, 0.f, 0.f);
            const float* envr = env + s * DP;
            #pragma unroll
            for (int i4 = 0; i4 < 16; ++i4) {
                const float4 e4 = *(const float4*)(envr + i4 * 4);
                const float* mb = Ml + (i4 * 8 + sel) * 64 + c4;  // rows i=4*i4+t at +t*128
                float4 m0 = *(const float4*)(mb);
                float4 m1 = *(const float4*)(mb + 128);
                float4 m2 = *(const float4*)(mb + 256);
                float4 m3 = *(const float4*)(mb + 384);
                FMA4(acc, e4.x, m0);
                FMA4(acc, e4.y, m1);
                FMA4(acc, e4.z, m2);
                FMA4(acc, e4.w, m3);
            }
            __syncthreads();  // all env reads done
            *(float4*)&env[s * DP + c4] = acc;
        }

        {   // psi = sum_j env[j] * right[j, cfg[:,-1]]  (thread reads only its own 4 cols)
            const int selL = cfg[s * 64 + 63];
            float p = 0.f;
            #pragma unroll
            for (int k = 0; k < 4; ++k) {
                const int j = c4 + k;
                p = fmaf(env[s * DP + j], rightG[j * 2 + selL], p);
            }
            red[s * 16 + c] = p;
        }
        __syncthreads();
        if (c == 0) {
            float psi = 0.f;
            #pragma unroll
            for (int k = 0; k < 16; ++k) psi += red[s * 16 + k];
            red[s * 16] = logf(fmaxf(psi * psi, 1e-12f));
        }
        __syncthreads();
        if (tid == 0) {
            float sum = 0.f;
            for (int k = 0; k < SPB; ++k) sum += red[k * 16];
            atomicAdd(&wsF[WS_PSISUM], sum);
        }
    } else {
        // ---------------- norm role: fwd (bid 0) / bwd (bid 1) chain, 31 sites each ----------------
        float* E     = (float*)smem;        // 64 x DP
        float* T     = E  + 64 * DP;        // 64 x DP
        float* Mp    = T  + 64 * DP;        // 64 x DP (one branch, maybe transposed)
        float* wred  = Mp + 64 * DP;        // 8
        float* bcast = wred + 8;            // 2

        const bool fwd = (bid == 0);
        const int r = tid >> 3;             // 0..63 output row
        const int c = tid & 7;              // col group of 8
        const int c8 = c * 8;

        for (int idx = tid; idx < 4096; idx += TPB) {
            const int i = idx >> 6, j = idx & 63;
            float v;
            if (fwd) v = leftG[i] * leftG[j] + leftG[64 + i] * leftG[64 + j];       // left^T left
            else     v = rightG[i*2] * rightG[j*2] + rightG[i*2+1] * rightG[j*2+1]; // right right^T
            E[i * DP + j] = v;
        }
        float lsum = 0.f;

        for (int k = 0; k < 31; ++k) {
            const int site = fwd ? k : (61 - k);
            const float* Mg = bulkG + (size_t)site * 8192;
            float4 b0 = make_float4(0.f,0.f,0.f,0.f);
            float4 b1 = make_float4(0.f,0.f,0.f,0.f);

            for (int p = 0; p < 2; ++p) {
                __syncthreads();  // prior readers of Mp/T done; E writes visible
                if (fwd) {
                    // Mp[i][j] = M_p[i][j]
                    for (int idx = tid; idx < 1024; idx += TPB) {
                        const int i = idx >> 4, jq = idx & 15;
                        float4 v = ((const float4*)Mg)[(i * 2 + p) * 16 + jq];
                        *(float4*)&Mp[i * DP + jq * 4] = v;
                    }
                } else {
                    // Mp[i][j] = M_p[j][i]  (so update becomes Mp^T E Mp, same as fwd)
                    for (int idx = tid; idx < 1024; idx += TPB) {
                        const int j = idx >> 4, iq = idx & 15;
                        float4 v = ((const float4*)Mg)[(j * 2 + p) * 16 + iq];
                        Mp[(iq * 4 + 0) * DP + j] = v.x;
                        Mp[(iq * 4 + 1) * DP + j] = v.y;
                        Mp[(iq * 4 + 2) * DP + j] = v.z;
                        Mp[(iq * 4 + 3) * DP + j] = v.w;
                    }
                }
                __syncthreads();

                // s1: T[r][c8..] = sum_i E[r][i] * Mp[i][c8..]
                {
                    float4 a0 = make_float4(0.f,0.f,0.f,0.f);
                    float4 a1 = make_float4(0.f,0.f,0.f,0.f);
                    const float* Er = E + r * DP;
                    const float* Mc = Mp + c8;
                    #pragma unroll 8
                    for (int i = 0; i < 64; ++i) {
                        const float e = Er[i];
                        float4 m0 = *(const float4*)(Mc + i * DP);
                        float4 m1 = *(const float4*)(Mc + i * DP + 4);
                        FMA4(a0, e, m0);
                        FMA4(a1, e, m1);
                    }
                    *(float4*)(T + r * DP + c8)     = a0;
                    *(float4*)(T + r * DP + c8 + 4) = a1;
                }
                __syncthreads();

                // s2: out[r][c8..] += sum_i T[i][r] * Mp[i][c8..]   ( = (Mp^T E Mp)^T, symmetric per p )
                {
                    const float* Mc = Mp + c8;
                    #pragma unroll 8
                    for (int i = 0; i < 64; ++i) {
                        const float t = T[i * DP + r];
                        float4 m0 = *(const float4*)(Mc + i * DP);
                        float4 m1 = *(const float4*)(Mc + i * DP + 4);
                        FMA4(b0, t, m0);
                        FMA4(b1, t, m1);
                    }
                }
            }

            // rescale like the reference: scale = max(|E'|, 1e-30)
            float m = fmaxf(fmaxf(fmaxf(fabsf(b0.x), fabsf(b0.y)), fmaxf(fabsf(b0.z), fabsf(b0.w))),
                            fmaxf(fmaxf(fabsf(b1.x), fabsf(b1.y)), fmaxf(fabsf(b1.z), fabsf(b1.w))));
            #pragma unroll
            for (int off = 32; off > 0; off >>= 1)
                m = fmaxf(m, __shfl_down(m, off));
            __syncthreads();                       // prior bcast readers done
            if ((tid & 63) == 0) wred[tid >> 6] = m;
            __syncthreads();
            if (tid == 0) {
                float mm = wred[0];
                #pragma unroll
                for (int w = 1; w < 8; ++w) mm = fmaxf(mm, wred[w]);
                const float scale = fmaxf(mm, 1e-30f);
                bcast[0] = scale;
                bcast[1] = 1.0f / scale;
            }
            __syncthreads();
            const float scale = bcast[0];
            const float inv   = bcast[1];
            lsum += logf(scale);
            float* Eo = E + r * DP + c8;
            Eo[0] = b0.x * inv; Eo[1] = b0.y * inv; Eo[2] = b0.z * inv; Eo[3] = b0.w * inv;
            Eo[4] = b1.x * inv; Eo[5] = b1.y * inv; Eo[6] = b1.z * inv; Eo[7] = b1.w * inv;
            // next site's first __syncthreads makes these visible before s1 reads
        }
        __syncthreads();
        float* dst = fwd ? (wsF + WS_E) : (wsF + WS_B);
        for (int idx = tid; idx < 4096; idx += TPB) {
            const int i = idx >> 6, j = idx & 63;
            dst[idx] = E[i * DP + j];
        }
        if (tid == 0) wsF[fwd ? WS_LSF : WS_LSB] = lsum;
    }
}

extern "C" __global__ void mps_finalize(const float* __restrict__ wsF, float* __restrict__ out)
{
    const int lane = threadIdx.x;  // 64 threads
    const float* E  = wsF + WS_E;
    const float* Bm = wsF + WS_B;
    float a = 0.f;
    #pragma unroll 8
    for (int j = 0; j < 64; ++j)
        a = fmaf(E[lane * 64 + j], Bm[lane * 64 + j], a);
    #pragma unroll
    for (int off = 32; off > 0; off >>= 1)
        a += __shfl_down(a, off);
    if (lane == 0) {
        const float z = fmaxf(a, 1e-30f);
        const float log_z = logf(z) + wsF[WS_LSF] + wsF[WS_LSB];
        out[0] = log_z - wsF[WS_PSISUM] * (1.0f / (float)BATCH);
    }
}

extern "C" void kernel_launch(void* const* d_in, const int* in_sizes, int n_in,
                              void* d_out, int out_size, void* d_ws, size_t ws_size,
                              hipStream_t stream)
{
    const int*   cfg   = (const int*)d_in[0];    // (8192, 64) int32
    const float* left  = (const float*)d_in[1];  // (2, 64)
    const float* bulk  = (const float*)d_in[2];  // (62, 64, 2, 64)
    const float* right = (const float*)d_in[3];  // (64, 2)
    float* wsF = (float*)d_ws;

    hipMemsetAsync(d_ws, 0, 64, stream);  // zero psi-sum + log-scale slots

    const size_t shbytes = 53248;  // max(psi 51712, norm 52304)
    // blocks 0,1 = norm chains (dispatch first, they are the long pole); 2..257 = psi (32 samples each)
    mps_main<<<dim3(258), dim3(TPB), shbytes, stream>>>(cfg, left, bulk, right, wsF);
    mps_finalize<<<dim3(1), dim3(64), 0, stream>>>(wsF, (float*)d_out);
}

// Round 2
// 179.814 us; speedup vs baseline: 2.7667x; 2.7667x over previous
//
#include <hip/hip_runtime.h>
#include <math.h>

#define NBULK 62
#define SB    72   // LDS row stride in bf16 elements (64 + 8 pad)

typedef __attribute__((ext_vector_type(8))) short bf8_t;   // 8 x bf16 (4 VGPRs)
typedef __attribute__((ext_vector_type(4))) float f4_t;    // 4 x fp32

#define MFMA(a, b, c) __builtin_amdgcn_mfma_f32_16x16x32_bf16((a), (b), (c), 0, 0, 0)

__device__ __forceinline__ unsigned short f2bf(float f) {
    unsigned int u = __float_as_uint(f);
    return (unsigned short)((u + 0x7FFFu + ((u >> 16) & 1u)) >> 16);
}
__device__ __forceinline__ float bf2f(unsigned short h) {
    return __uint_as_float(((unsigned int)h) << 16);
}

// ---- ws byte layout ----
// 0:   psisum (f32), 4: lsf, 8: lsb
// 4096:   E_fwd fp32[4096]
// 24576:  E_bwd fp32[4096]
// 45056:  BT bf16 [62][128][64]  (BT[s][p*64+n][k] = bulk[s][k][p][n])
// 1060864: MR bf16 [62][2][64][64] (MR[s][p][k][j] = bulk[s][k][p][j])
#define WS_E_OFF   1024     // float index
#define WS_B_OFF   6144     // float index
#define WS_BT_OFF  45056    // bytes
#define WS_MR_OFF  1060864  // bytes

extern "C" __global__ __launch_bounds__(256)
void mps_precompute(const float* __restrict__ bulkG,
                    unsigned short* __restrict__ BTg,
                    unsigned short* __restrict__ MRg)
{
    const int s = blockIdx.x, tid = threadIdx.x;
    const float4* src = (const float4*)(bulkG + (size_t)s * 8192);
    for (int c = 0; c < 8; ++c) {
        int idx = tid + c * 256;            // 0..2047
        float4 v = src[idx];
        int f  = idx * 4;
        int kk = f >> 7;                    // 0..63
        int p  = (f >> 6) & 1;
        int j  = f & 63;                    // multiple of 4
        unsigned short b0 = f2bf(v.x), b1 = f2bf(v.y), b2 = f2bf(v.z), b3 = f2bf(v.w);
        ushort4 pk; pk.x = b0; pk.y = b1; pk.z = b2; pk.w = b3;
        *(ushort4*)(MRg + (((size_t)s * 2 + p) * 64 + kk) * 64 + j) = pk;
        size_t bt = ((size_t)s * 128 + p * 64 + j) * 64 + kk;
        BTg[bt]       = b0;
        BTg[bt + 64]  = b1;
        BTg[bt + 128] = b2;
        BTg[bt + 192] = b3;
    }
}

extern "C" __global__ __launch_bounds__(256)
void mps_main(const int* __restrict__ cfgG, const float* __restrict__ leftG,
              const float* __restrict__ rightG, float* __restrict__ wsF,
              const unsigned short* __restrict__ BTg,
              const unsigned short* __restrict__ MRg)
{
    extern __shared__ char smem[];
    const int tid  = threadIdx.x;
    const int bid  = blockIdx.x;
    const int wv   = tid >> 6;
    const int lane = tid & 63;
    const int quad = lane >> 4;
    const int ln   = lane & 15;

    if (bid >= 2) {
        // ================= psi role: 64 samples, GEMM env @ [M0|M1] + select =================
        unsigned short* env  = (unsigned short*)smem;      // 64 x SB
        unsigned short* Bt   = env + 64 * SB;              // 128 x SB
        unsigned char*  selT = (unsigned char*)(Bt + 128 * SB); // [site_col][sample] 64x64
        float*          red  = (float*)(selT + 4096);      // 256

        const int s0 = (bid - 2) * 64;
        for (int c = 0; c < 16; ++c) {
            int idx = tid + c * 256;                       // linear over (m, i)
            int m = idx >> 6, i = idx & 63;
            selT[i * 64 + m] = (unsigned char)cfgG[(size_t)(s0 + m) * 64 + i];
        }
        __syncthreads();
        {   // env0 = left[sel0]
            int m = tid >> 2, kq = tid & 3;
            int sel = selT[m];                             // col 0
            const float* lp = leftG + sel * 64 + kq * 16;
            for (int j = 0; j < 16; ++j)
                env[m * SB + kq * 16 + j] = f2bf(lp[j]);
        }

        for (int t = 0; t < NBULK; ++t) {
            // stage Bt[n][k] from BT[site]
            const unsigned short* src = BTg + (size_t)t * 8192;
            for (int c = 0; c < 4; ++c) {
                int ch = tid + c * 256;
                int n = ch >> 3, k8 = ch & 7;
                uint4 v = *(const uint4*)(src + n * 64 + k8 * 8);
                *(uint4*)(Bt + n * SB + k8 * 8) = v;
            }
            __syncthreads();                                // Bt ready; env writes visible

            bf8_t Af[4][2];
            #pragma unroll
            for (int mt = 0; mt < 4; ++mt)
                #pragma unroll
                for (int h = 0; h < 2; ++h)
                    Af[mt][h] = *(const bf8_t*)(env + (mt * 16 + ln) * SB + h * 32 + quad * 8);

            f4_t acc[2][4];
            #pragma unroll
            for (int c = 0; c < 2; ++c) {
                int nt = wv * 2 + c;
                bf8_t B0 = *(const bf8_t*)(Bt + (nt * 16 + ln) * SB + quad * 8);
                bf8_t B1 = *(const bf8_t*)(Bt + (nt * 16 + ln) * SB + 32 + quad * 8);
                #pragma unroll
                for (int mt = 0; mt < 4; ++mt) {
                    f4_t a = {0.f, 0.f, 0.f, 0.f};
                    a = MFMA(Af[mt][0], B0, a);
                    a = MFMA(Af[mt][1], B1, a);
                    acc[c][mt] = a;
                }
            }
            __syncthreads();                                // all frag reads done

            const int selcol = t + 1;
            #pragma unroll
            for (int c = 0; c < 2; ++c) {
                int nt = wv * 2 + c;
                int b  = nt >> 2;
                int colp = (nt & 3) * 16 + ln;
                #pragma unroll
                for (int mt = 0; mt < 4; ++mt) {
                    unsigned int sv = *(const unsigned int*)(selT + selcol * 64 + mt * 16 + quad * 4);
                    #pragma unroll
                    for (int r = 0; r < 4; ++r) {
                        int row = mt * 16 + quad * 4 + r;
                        if ((int)((sv >> (8 * r)) & 0xFF) == b)
                            env[row * SB + colp] = f2bf(acc[c][mt][r]);
                    }
                }
            }
        }
        __syncthreads();
        {   // psi = env . right[:, selL]
            int m = tid >> 2, part = tid & 3;
            int selL = selT[63 * 64 + m];
            float ps = 0.f;
            for (int j = 0; j < 16; ++j) {
                int k = part * 16 + j;
                ps = fmaf(bf2f(env[m * SB + k]), rightG[k * 2 + selL], ps);
            }
            red[tid] = ps;
        }
        __syncthreads();
        if (tid < 64) {
            float psi = red[tid * 4] + red[tid * 4 + 1] + red[tid * 4 + 2] + red[tid * 4 + 3];
            float lp = logf(fmaxf(psi * psi, 1e-12f));
            #pragma unroll
            for (int off = 32; off > 0; off >>= 1)
                lp += __shfl_down(lp, off);
            if (tid == 0) atomicAdd(&wsF[0], lp);
        }
    } else {
        // ================= norm role: MFMA transfer chain =================
        unsigned short* Ebf = (unsigned short*)smem;       // 64 x SB
        unsigned short* St0 = Ebf + 64 * SB;
        unsigned short* St1 = St0 + 64 * SB;
        unsigned short* Mst = St1 + 64 * SB;               // 128 x SB
        float* wred = (float*)(Mst + 128 * SB);            // 4

        const bool fwd = (bid == 0);
        {   // E0
            int i = tid >> 2, jq = tid & 3;
            for (int jj = 0; jj < 16; ++jj) {
                int j = jq * 16 + jj;
                float v;
                if (fwd) v = leftG[i] * leftG[j] + leftG[64 + i] * leftG[64 + j];
                else     v = rightG[i * 2] * rightG[j * 2] + rightG[i * 2 + 1] * rightG[j * 2 + 1];
                Ebf[i * SB + j] = f2bf(v);
            }
        }
        float lsum = 0.f;
        const int p   = wv >> 1;
        const int ntb = (wv & 1) * 2;
        const int mta = (wv >> 1) * 2;
        const int nta = (wv & 1) * 2;
        unsigned short* Stp = p ? St1 : St0;

        for (int k = 0; k < 31; ++k) {
            const int site = fwd ? k : (61 - k);
            const unsigned short* src = (fwd ? BTg : MRg) + (size_t)site * 8192;
            for (int c = 0; c < 4; ++c) {
                int ch = tid + c * 256;
                int n = ch >> 3, k8 = ch & 7;
                uint4 v = *(const uint4*)(src + n * 64 + k8 * 8);
                *(uint4*)(Mst + n * SB + k8 * 8) = v;
            }
            __syncthreads();   // A: Mst + Ebf ready

            // stage1: S_p = E * Op_p   (write transposed St_p[n][m])
            {
                bf8_t Af[4][2];
                #pragma unroll
                for (int mt = 0; mt < 4; ++mt)
                    #pragma unroll
                    for (int h = 0; h < 2; ++h)
                        Af[mt][h] = *(const bf8_t*)(Ebf + (mt * 16 + ln) * SB + h * 32 + quad * 8);
                #pragma unroll
                for (int c = 0; c < 2; ++c) {
                    int nt = ntb + c;
                    bf8_t B0 = *(const bf8_t*)(Mst + (p * 64 + nt * 16 + ln) * SB + quad * 8);
                    bf8_t B1 = *(const bf8_t*)(Mst + (p * 64 + nt * 16 + ln) * SB + 32 + quad * 8);
                    #pragma unroll
                    for (int mt = 0; mt < 4; ++mt) {
                        f4_t a = {0.f, 0.f, 0.f, 0.f};
                        a = MFMA(Af[mt][0], B0, a);
                        a = MFMA(Af[mt][1], B1, a);
                        ushort4 pk;
                        pk.x = f2bf(a[0]); pk.y = f2bf(a[1]); pk.z = f2bf(a[2]); pk.w = f2bf(a[3]);
                        *(ushort4*)(Stp + (nt * 16 + ln) * SB + mt * 16 + quad * 4) = pk;
                    }
                }
            }
            __syncthreads();   // B: St ready

            // stage2: E' = sum_p Op_p^T-side * S_p   (2x2 tile block per wave)
            f4_t acc[2][2];
            {
                bf8_t Aw[2][2][2], Bw[2][2][2];
                #pragma unroll
                for (int pp = 0; pp < 2; ++pp)
                    #pragma unroll
                    for (int mi = 0; mi < 2; ++mi)
                        #pragma unroll
                        for (int h = 0; h < 2; ++h)
                            Aw[pp][mi][h] = *(const bf8_t*)(Mst + (pp * 64 + (mta + mi) * 16 + ln) * SB + h * 32 + quad * 8);
                #pragma unroll
                for (int pp = 0; pp < 2; ++pp)
                    #pragma unroll
                    for (int ni = 0; ni < 2; ++ni)
                        #pragma unroll
                        for (int h = 0; h < 2; ++h)
                            Bw[pp][ni][h] = *(const bf8_t*)((pp ? St1 : St0) + ((nta + ni) * 16 + ln) * SB + h * 32 + quad * 8);
                #pragma unroll
                for (int mi = 0; mi < 2; ++mi)
                    #pragma unroll
                    for (int ni = 0; ni < 2; ++ni) {
                        f4_t a = {0.f, 0.f, 0.f, 0.f};
                        #pragma unroll
                        for (int pp = 0; pp < 2; ++pp)
                            #pragma unroll
                            for (int h = 0; h < 2; ++h)
                                a = MFMA(Aw[pp][mi][h], Bw[pp][ni][h], a);
                        acc[mi][ni] = a;
                    }
                float mx = 0.f;
                #pragma unroll
                for (int mi = 0; mi < 2; ++mi)
                    #pragma unroll
                    for (int ni = 0; ni < 2; ++ni)
                        #pragma unroll
                        for (int r = 0; r < 4; ++r)
                            mx = fmaxf(mx, fabsf(acc[mi][ni][r]));
                #pragma unroll
                for (int off = 32; off > 0; off >>= 1)
                    mx = fmaxf(mx, __shfl_down(mx, off));
                if (lane == 0) wred[wv] = mx;
            }
            __syncthreads();   // C: wred ready, Mst/St reads done

            float mm = fmaxf(fmaxf(wred[0], wred[1]), fmaxf(wred[2], wred[3]));
            float scale = fmaxf(mm, 1e-30f);
            float inv = 1.0f / scale;
            if (tid == 0) lsum += logf(scale);
            #pragma unroll
            for (int mi = 0; mi < 2; ++mi)
                #pragma unroll
                for (int ni = 0; ni < 2; ++ni)
                    #pragma unroll
                    for (int r = 0; r < 4; ++r) {
                        int row = (mta + mi) * 16 + quad * 4 + r;
                        int col = (nta + ni) * 16 + ln;
                        Ebf[row * SB + col] = f2bf(acc[mi][ni][r] * inv);
                    }
        }
        __syncthreads();
        float* dst = wsF + (fwd ? WS_E_OFF : WS_B_OFF);
        for (int c = 0; c < 16; ++c) {
            int idx = tid + c * 256;
            dst[idx] = bf2f(Ebf[(idx >> 6) * SB + (idx & 63)]);
        }
        if (tid == 0) wsF[fwd ? 1 : 2] = lsum;
    }
}

extern "C" __global__ void mps_finalize(const float* __restrict__ wsF, float* __restrict__ out)
{
    const int lane = threadIdx.x;  // 64 threads
    const float* E  = wsF + WS_E_OFF;
    const float* Bm = wsF + WS_B_OFF;
    float a = 0.f;
    #pragma unroll 8
    for (int j = 0; j < 64; ++j)
        a = fmaf(E[lane * 64 + j], Bm[lane * 64 + j], a);
    #pragma unroll
    for (int off = 32; off > 0; off >>= 1)
        a += __shfl_down(a, off);
    if (lane == 0) {
        const float z = fmaxf(a, 1e-30f);
        const float log_z = logf(z) + wsF[1] + wsF[2];
        out[0] = log_z - wsF[0] * (1.0f / 8192.0f);
    }
}

extern "C" void kernel_launch(void* const* d_in, const int* in_sizes, int n_in,
                              void* d_out, int out_size, void* d_ws, size_t ws_size,
                              hipStream_t stream)
{
    const int*   cfg   = (const int*)d_in[0];    // (8192, 64) int32
    const float* left  = (const float*)d_in[1];  // (2, 64)
    const float* bulk  = (const float*)d_in[2];  // (62, 64, 2, 64)
    const float* right = (const float*)d_in[3];  // (64, 2)
    float* wsF = (float*)d_ws;
    unsigned short* BTg = (unsigned short*)((char*)d_ws + WS_BT_OFF);
    unsigned short* MRg = (unsigned short*)((char*)d_ws + WS_MR_OFF);

    hipMemsetAsync(d_ws, 0, 16, stream);
    mps_precompute<<<dim3(62), dim3(256), 0, stream>>>(bulk, BTg, MRg);
    // blocks 0,1 = norm chains (long pole, dispatch first); 2..129 = psi (64 samples each)
    mps_main<<<dim3(130), dim3(256), 46336, stream>>>(cfg, left, right, wsF, BTg, MRg);
    mps_finalize<<<dim3(1), dim3(64), 0, stream>>>(wsF, (float*)d_out);
}

// Round 3
// 119.390 us; speedup vs baseline: 4.1669x; 1.5061x over previous
//
#include <hip/hip_runtime.h>
#include <math.h>

#define NBULK 62
#define SB    72   // padded LDS row stride (bf16) for env/E/St

typedef __attribute__((ext_vector_type(8))) short bf8_t;   // 8 x bf16
typedef __attribute__((ext_vector_type(4))) float f4_t;    // 4 x fp32

#define MFMA(a, b, c) __builtin_amdgcn_mfma_f32_16x16x32_bf16((a), (b), (c), 0, 0, 0)

__device__ __forceinline__ unsigned short f2bf(float f) {
    unsigned int u = __float_as_uint(f);
    return (unsigned short)((u + 0x7FFFu + ((u >> 16) & 1u)) >> 16);
}
__device__ __forceinline__ float bf2f(unsigned short h) {
    return __uint_as_float(((unsigned int)h) << 16);
}

// async global->LDS, 16B per lane; lptr must be wave-uniform (HW adds lane*16)
__device__ __forceinline__ void gload16(const void* g, void* l) {
    __builtin_amdgcn_global_load_lds(
        (const __attribute__((address_space(1))) unsigned int*)g,
        (__attribute__((address_space(3))) unsigned int*)l, 16, 0, 0);
}

// ---- ws layout ----
// floats: [0]=psisum [1]=lsf [2]=lsb ; E_fwd at float 1024, E_bwd at float 6144
// bytes:  BT (swizzled, 62*16KB) at 45056 ; MR (swizzled) at 1060864
#define WS_E_OFF   1024
#define WS_B_OFF   6144
#define WS_BT_OFF  45056
#define WS_MR_OFF  1060864

// swizzled offset of element (row n, col k) inside a 128x64 bf16 tile:
//   n*64 + ((k>>3 ^ (n&7))<<3 | (k&7))
// consumers read 8-contig k-group g at: n*64 + ((g ^ (n&7))<<3)

extern "C" __global__ __launch_bounds__(256)
void mps_precompute(const float* __restrict__ bulkG,
                    unsigned short* __restrict__ BTg,
                    unsigned short* __restrict__ MRg)
{
    __shared__ unsigned short BTl[8192];
    __shared__ unsigned short MRl[8192];
    const int s = blockIdx.x, tid = threadIdx.x;
    const float4* src = (const float4*)(bulkG + (size_t)s * 8192);
    for (int c = 0; c < 8; ++c) {
        int idx = tid + c * 256;            // 0..2047
        float4 v = src[idx];
        int f  = idx * 4;
        int kk = f >> 7;                    // 0..63
        int p  = (f >> 6) & 1;
        int j  = f & 63;                    // multiple of 4
        unsigned short b0 = f2bf(v.x), b1 = f2bf(v.y), b2 = f2bf(v.z), b3 = f2bf(v.w);
        // MR row n = p*64+kk holds M_p[kk][:]
        int n = p * 64 + kk;
        int off = n * 64 + (((j >> 3) ^ (n & 7)) << 3) + (j & 7);
        MRl[off + 0] = b0; MRl[off + 1] = b1; MRl[off + 2] = b2; MRl[off + 3] = b3;
        // BT rows n' = p*64 + j.. hold columns of M_p
        unsigned short bb[4] = {b0, b1, b2, b3};
        #pragma unroll
        for (int t2 = 0; t2 < 4; ++t2) {
            int n2 = p * 64 + j + t2;
            BTl[n2 * 64 + (((kk >> 3) ^ (n2 & 7)) << 3) + (kk & 7)] = bb[t2];
        }
    }
    __syncthreads();
    const uint4* bt4 = (const uint4*)BTl;
    const uint4* mr4 = (const uint4*)MRl;
    uint4* btg = (uint4*)(BTg + (size_t)s * 8192);
    uint4* mrg = (uint4*)(MRg + (size_t)s * 8192);
    for (int c = 0; c < 4; ++c) {
        int idx = tid + c * 256;
        btg[idx] = bt4[idx];
        mrg[idx] = mr4[idx];
    }
}

extern "C" __global__ __launch_bounds__(256)
void mps_main(const int* __restrict__ cfgG, const float* __restrict__ leftG,
              const float* __restrict__ rightG, float* __restrict__ wsF,
              const unsigned short* __restrict__ BTg,
              const unsigned short* __restrict__ MRg)
{
    extern __shared__ char smem[];
    unsigned short* smem16 = (unsigned short*)smem;
    const int tid  = threadIdx.x;
    const int bid  = blockIdx.x;
    const int wv   = tid >> 6;
    const int lane = tid & 63;
    const int quad = lane >> 4;
    const int ln   = lane & 15;

    if (bid >= 2) {
        // ========== psi: 64 samples/block; each wave owns 16 samples, all 64 cols ==========
        unsigned short* Bb0  = smem16;                 // 8192 bf16 (swizzled tile)
        unsigned short* Bb1  = Bb0 + 8192;
        unsigned short* env  = Bb1 + 8192;             // 64 x SB
        unsigned char*  selT = (unsigned char*)(env + 64 * SB);  // [col][sample] 64x64

        const int s0 = (bid - 2) * 64;
        {   // fill selT (coalesced int4 reads, byte scatter to LDS)
            int m = tid >> 2, part = tid & 3;
            const int* row = cfgG + (size_t)(s0 + m) * 64 + part * 16;
            #pragma unroll
            for (int q = 0; q < 4; ++q) {
                int4 v = *(const int4*)(row + q * 4);
                int cb = part * 16 + q * 4;
                selT[(cb + 0) * 64 + m] = (unsigned char)v.x;
                selT[(cb + 1) * 64 + m] = (unsigned char)v.y;
                selT[(cb + 2) * 64 + m] = (unsigned char)v.z;
                selT[(cb + 3) * 64 + m] = (unsigned char)v.w;
            }
        }
        {   // prefetch tile 0
            const char* g0 = (const char*)BTg;
            for (int c = 0; c < 4; ++c) {
                int chunk = wv * 4 + c;
                gload16(g0 + chunk * 1024 + (size_t)lane * 16, (char*)Bb0 + chunk * 1024);
            }
        }
        __syncthreads();   // selT ready

        bf8_t Af[2];
        {   // env0 fragments direct from left (A layout: m=ln, k=h*32+quad*8+j)
            int sel0 = selT[0 * 64 + wv * 16 + ln];
            const float* lp0 = leftG + sel0 * 64;
            #pragma unroll
            for (int h = 0; h < 2; ++h) {
                float4 a = *(const float4*)(lp0 + h * 32 + quad * 8);
                float4 b = *(const float4*)(lp0 + h * 32 + quad * 8 + 4);
                bf8_t t;
                t[0] = (short)f2bf(a.x); t[1] = (short)f2bf(a.y);
                t[2] = (short)f2bf(a.z); t[3] = (short)f2bf(a.w);
                t[4] = (short)f2bf(b.x); t[5] = (short)f2bf(b.y);
                t[6] = (short)f2bf(b.z); t[7] = (short)f2bf(b.w);
                Af[h] = t;
            }
        }

        for (int t = 0; t < NBULK; ++t) {
            __syncthreads();   // tile t resident in Bb[t&1]
            unsigned short* B = (t & 1) ? Bb1 : Bb0;
            if (t + 1 < NBULK) {   // prefetch t+1 into other buffer
                const char* gn = (const char*)(BTg + (size_t)(t + 1) * 8192);
                char* l = (char*)((t & 1) ? Bb0 : Bb1);
                for (int c = 0; c < 4; ++c) {
                    int chunk = wv * 4 + c;
                    gload16(gn + chunk * 1024 + (size_t)lane * 16, l + chunk * 1024);
                }
            }
            // B fragments: branch b2, col tile ct, k-half h  (swizzled, conflict-free)
            bf8_t Bf[2][4][2];
            #pragma unroll
            for (int b2 = 0; b2 < 2; ++b2)
                #pragma unroll
                for (int ct = 0; ct < 4; ++ct) {
                    int row = b2 * 64 + ct * 16 + ln;
                    #pragma unroll
                    for (int h = 0; h < 2; ++h)
                        Bf[b2][ct][h] = *(const bf8_t*)(B + row * 64 + (((h * 4 + quad) ^ (ln & 7)) << 3));
                }
            f4_t acc[2][4];
            #pragma unroll
            for (int b2 = 0; b2 < 2; ++b2)
                #pragma unroll
                for (int ct = 0; ct < 4; ++ct) {
                    f4_t a = {0.f, 0.f, 0.f, 0.f};
                    a = MFMA(Af[0], Bf[b2][ct][0], a);
                    a = MFMA(Af[1], Bf[b2][ct][1], a);
                    acc[b2][ct] = a;
                }
            // in-register branch select, write env (C layout: row=quad*4+r, col=ct*16+ln)
            unsigned int sv = *(const unsigned int*)(selT + (t + 1) * 64 + wv * 16 + quad * 4);
            #pragma unroll
            for (int ct = 0; ct < 4; ++ct)
                #pragma unroll
                for (int r = 0; r < 4; ++r) {
                    float v = ((sv >> (8 * r)) & 1u) ? acc[1][ct][r] : acc[0][ct][r];
                    env[(wv * 16 + quad * 4 + r) * SB + ct * 16 + ln] = f2bf(v);
                }
            // reload A frags (same-wave DS ordering guarantees RAW)
            Af[0] = *(const bf8_t*)(env + (wv * 16 + ln) * SB + quad * 8);
            Af[1] = *(const bf8_t*)(env + (wv * 16 + ln) * SB + 32 + quad * 8);
        }
        {   // psi = env . right[:, selL]; wave-local reduction
            int selL = selT[63 * 64 + wv * 16 + ln];
            bf8_t e0 = *(const bf8_t*)(env + (wv * 16 + ln) * SB + quad * 16);
            bf8_t e1 = *(const bf8_t*)(env + (wv * 16 + ln) * SB + quad * 16 + 8);
            float p = 0.f;
            #pragma unroll
            for (int j = 0; j < 8; ++j)
                p = fmaf(bf2f((unsigned short)e0[j]), rightG[(quad * 16 + j) * 2 + selL], p);
            #pragma unroll
            for (int j = 0; j < 8; ++j)
                p = fmaf(bf2f((unsigned short)e1[j]), rightG[(quad * 16 + 8 + j) * 2 + selL], p);
            p += __shfl_xor(p, 16);
            p += __shfl_xor(p, 32);            // full psi in every lane of its ln-group
            float lp = logf(fmaxf(p * p, 1e-12f));
            lp += __shfl_xor(lp, 1); lp += __shfl_xor(lp, 2);
            lp += __shfl_xor(lp, 4); lp += __shfl_xor(lp, 8);
            if (lane == 0) atomicAdd(&wsF[0], lp);
        }
    } else {
        // ========== norm chain: fwd (bid 0) / bwd (bid 1), 31 sites, deferred rescale ==========
        unsigned short* Ebf = smem16;                    // 64 x SB
        unsigned short* St0 = Ebf + 64 * SB;
        unsigned short* St1 = St0 + 64 * SB;
        unsigned short* Ms0 = St1 + 64 * SB;             // 8192 (swizzled tile)
        unsigned short* Ms1 = Ms0 + 8192;
        float* wred = (float*)(Ms1 + 8192);              // [2][4]

        const bool fwd = (bid == 0);
        const unsigned short* srcbase = fwd ? BTg : MRg;
        {   // E0
            int i = tid >> 2, jq = tid & 3;
            for (int jj = 0; jj < 16; ++jj) {
                int j = jq * 16 + jj;
                float v;
                if (fwd) v = leftG[i] * leftG[j] + leftG[64 + i] * leftG[64 + j];
                else     v = rightG[i * 2] * rightG[j * 2] + rightG[i * 2 + 1] * rightG[j * 2 + 1];
                Ebf[i * SB + j] = f2bf(v);
            }
        }
        {   // prefetch site 0
            int st = fwd ? 0 : 61;
            const char* g = (const char*)(srcbase + (size_t)st * 8192);
            for (int c = 0; c < 4; ++c) {
                int chunk = wv * 4 + c;
                gload16(g + chunk * 1024 + (size_t)lane * 16, (char*)Ms0 + chunk * 1024);
            }
        }
        float lsum = 0.f;
        const int p   = wv >> 1;
        const int ntb = (wv & 1) * 2;
        const int mta = (wv >> 1) * 2;
        const int nta = (wv & 1) * 2;
        unsigned short* Stp = p ? St1 : St0;

        for (int k = 0; k < 31; ++k) {
            __syncthreads();   // Ms[k&1] resident; Ebf(k-1), wred(k-1) visible
            unsigned short* M = (k & 1) ? Ms1 : Ms0;
            if (k + 1 < 31) {
                int sn = fwd ? (k + 1) : (61 - (k + 1));
                const char* g = (const char*)(srcbase + (size_t)sn * 8192);
                char* l = (char*)((k & 1) ? Ms0 : Ms1);
                for (int c = 0; c < 4; ++c) {
                    int chunk = wv * 4 + c;
                    gload16(g + chunk * 1024 + (size_t)lane * 16, l + chunk * 1024);
                }
            }
            float inv = 1.f;
            if (k > 0) {
                const float* wp = wred + ((k - 1) & 1) * 4;
                float mm = fmaxf(fmaxf(wp[0], wp[1]), fmaxf(wp[2], wp[3]));
                float sc = fmaxf(mm, 1e-30f);
                inv = 1.f / sc;
                if (tid == 0) lsum += logf(sc);
            }
            // stage1: S_p = E * Op_p  (St stores transposed)
            {
                bf8_t Af2[4][2];
                #pragma unroll
                for (int mt = 0; mt < 4; ++mt)
                    #pragma unroll
                    for (int h = 0; h < 2; ++h)
                        Af2[mt][h] = *(const bf8_t*)(Ebf + (mt * 16 + ln) * SB + h * 32 + quad * 8);
                #pragma unroll
                for (int c = 0; c < 2; ++c) {
                    int nt = ntb + c;
                    int row = p * 64 + nt * 16 + ln;
                    bf8_t B0 = *(const bf8_t*)(M + row * 64 + (((0 + quad) ^ (ln & 7)) << 3));
                    bf8_t B1 = *(const bf8_t*)(M + row * 64 + (((4 + quad) ^ (ln & 7)) << 3));
                    #pragma unroll
                    for (int mt = 0; mt < 4; ++mt) {
                        f4_t a = {0.f, 0.f, 0.f, 0.f};
                        a = MFMA(Af2[mt][0], B0, a);
                        a = MFMA(Af2[mt][1], B1, a);
                        ushort4 pk;
                        pk.x = f2bf(a[0]); pk.y = f2bf(a[1]); pk.z = f2bf(a[2]); pk.w = f2bf(a[3]);
                        *(ushort4*)(Stp + (nt * 16 + ln) * SB + mt * 16 + quad * 4) = pk;
                    }
                }
            }
            __syncthreads();   // St ready; stage1 Ebf reads done
            // stage2: E' = sum_p Op_p^T-side * S_p ; scale by prev-site max; write Ebf
            {
                bf8_t Aw[2][2][2], Bw[2][2][2];
                #pragma unroll
                for (int pp = 0; pp < 2; ++pp)
                    #pragma unroll
                    for (int mi = 0; mi < 2; ++mi)
                        #pragma unroll
                        for (int h = 0; h < 2; ++h)
                            Aw[pp][mi][h] = *(const bf8_t*)(M + (pp * 64 + (mta + mi) * 16 + ln) * 64
                                                              + (((h * 4 + quad) ^ (ln & 7)) << 3));
                #pragma unroll
                for (int pp = 0; pp < 2; ++pp)
                    #pragma unroll
                    for (int ni = 0; ni < 2; ++ni)
                        #pragma unroll
                        for (int h = 0; h < 2; ++h)
                            Bw[pp][ni][h] = *(const bf8_t*)((pp ? St1 : St0)
                                                            + ((nta + ni) * 16 + ln) * SB + h * 32 + quad * 8);
                float mx = 0.f;
                #pragma unroll
                for (int mi = 0; mi < 2; ++mi)
                    #pragma unroll
                    for (int ni = 0; ni < 2; ++ni) {
                        f4_t a = {0.f, 0.f, 0.f, 0.f};
                        #pragma unroll
                        for (int pp = 0; pp < 2; ++pp)
                            #pragma unroll
                            for (int h = 0; h < 2; ++h)
                                a = MFMA(Aw[pp][mi][h], Bw[pp][ni][h], a);
                        #pragma unroll
                        for (int r = 0; r < 4; ++r) {
                            float val = a[r] * inv;
                            mx = fmaxf(mx, fabsf(val));
                            Ebf[((mta + mi) * 16 + quad * 4 + r) * SB + (nta + ni) * 16 + ln] = f2bf(val);
                        }
                    }
                #pragma unroll
                for (int off = 32; off > 0; off >>= 1)
                    mx = fmaxf(mx, __shfl_xor(mx, off));
                if (lane == 0) wred[(k & 1) * 4 + wv] = mx;
            }
        }
        __syncthreads();
        float* dst = wsF + (fwd ? WS_E_OFF : WS_B_OFF);
        for (int c = 0; c < 16; ++c) {
            int idx = tid + c * 256;
            dst[idx] = bf2f(Ebf[(idx >> 6) * SB + (idx & 63)]);
        }
        if (tid == 0) wsF[fwd ? 1 : 2] = lsum;
    }
}

extern "C" __global__ void mps_finalize(const float* __restrict__ wsF, float* __restrict__ out)
{
    const int lane = threadIdx.x;  // 64 threads
    const float* E  = wsF + WS_E_OFF;
    const float* Bm = wsF + WS_B_OFF;
    float a = 0.f;
    #pragma unroll 8
    for (int j = 0; j < 64; ++j)
        a = fmaf(E[lane * 64 + j], Bm[lane * 64 + j], a);
    #pragma unroll
    for (int off = 32; off > 0; off >>= 1)
        a += __shfl_down(a, off);
    if (lane == 0) {
        const float z = fmaxf(a, 1e-30f);
        const float log_z = logf(z) + wsF[1] + wsF[2];
        out[0] = log_z - wsF[0] * (1.0f / 8192.0f);
    }
}

extern "C" void kernel_launch(void* const* d_in, const int* in_sizes, int n_in,
                              void* d_out, int out_size, void* d_ws, size_t ws_size,
                              hipStream_t stream)
{
    const int*   cfg   = (const int*)d_in[0];    // (8192, 64) int32
    const float* left  = (const float*)d_in[1];  // (2, 64)
    const float* bulk  = (const float*)d_in[2];  // (62, 64, 2, 64)
    const float* right = (const float*)d_in[3];  // (64, 2)
    float* wsF = (float*)d_ws;
    unsigned short* BTg = (unsigned short*)((char*)d_ws + WS_BT_OFF);
    unsigned short* MRg = (unsigned short*)((char*)d_ws + WS_MR_OFF);

    hipMemsetAsync(d_ws, 0, 16, stream);
    mps_precompute<<<dim3(62), dim3(256), 0, stream>>>(bulk, BTg, MRg);
    // blocks 0,1 = norm chains (long pole, dispatch first); 2..129 = psi (64 samples each)
    mps_main<<<dim3(130), dim3(256), 60480, stream>>>(cfg, left, right, wsF, BTg, MRg);
    mps_finalize<<<dim3(1), dim3(64), 0, stream>>>(wsF, (float*)d_out);
}